// Round 3
// baseline (296.184 us; speedup 1.0000x reference)
//
#include <hip/hip_runtime.h>

typedef unsigned short u16;
typedef unsigned int   u32;
typedef unsigned long long u64;
typedef __bf16  bf16x8 __attribute__((ext_vector_type(8)));
typedef float   f32x4  __attribute__((ext_vector_type(4)));

// ---------- helpers ----------
__device__ __forceinline__ u16 f2bf(float f) {   // round-to-nearest-even
  u32 u = __builtin_bit_cast(u32, f);
  u += 0x7FFFu + ((u >> 16) & 1u);
  return (u16)(u >> 16);
}
__device__ __forceinline__ u32 pack2(float lo, float hi) {
  return (u32)f2bf(lo) | ((u32)f2bf(hi) << 16);
}

// async global->LDS, 16B per lane; LDS dest = wave-uniform base + lane*16
__device__ __forceinline__ void gload_lds16(const u16* g, u16* l) {
  __builtin_amdgcn_global_load_lds((const __attribute__((address_space(1))) void*)g,
                                   (__attribute__((address_space(3))) void*)l,
                                   16, 0, 0);
}

// ---------- prep: x fp32->bf16  AND  W fp32 -> bf16 transposed ----------
__global__ __launch_bounds__(256) void prep(const float* __restrict__ x,
                                            const float* __restrict__ w,
                                            u16* __restrict__ Xb,
                                            u16* __restrict__ Wt) {
  if (blockIdx.z < 3) {
    if (blockIdx.x >= 12 || blockIdx.y >= 12) return;
    __shared__ u16 t[64][65];
    const float* iz = w + (size_t)blockIdx.z * 768 * 768;
    u16* oz = Wt + (size_t)blockIdx.z * 768 * 768;
    const int tx = threadIdx.x & 63, ty = threadIdx.x >> 6;
    const int r0 = blockIdx.y * 64, c0 = blockIdx.x * 64;
#pragma unroll
    for (int rr = ty; rr < 64; rr += 4)
      t[rr][tx] = f2bf(iz[(size_t)(r0 + rr) * 768 + c0 + tx]);
    __syncthreads();
#pragma unroll
    for (int rr = ty; rr < 64; rr += 4)
      oz[(size_t)(c0 + rr) * 768 + r0 + tx] = t[tx][rr];
  } else {
    const size_t lin = (size_t)(blockIdx.z - 3) * 256 + blockIdx.y * 16 + blockIdx.x;
    const size_t i = lin * 256 + threadIdx.x;       // 8 elems per thread
    const float4* in4 = (const float4*)x;
    float4 a = in4[2 * i], b = in4[2 * i + 1];
    uint4 o;
    o.x = pack2(a.x, a.y); o.y = pack2(a.z, a.w);
    o.z = pack2(b.x, b.y); o.w = pack2(b.z, b.w);
    ((uint4*)Xb)[i] = o;
  }
}

// ---------- batched GEMM: C[m][n] = sum_k A[m][k] * Bt[n][k] ----------
// 256x256 tile, BK=64, 512 thr (8 waves, 2Mx4N), 160 KiB LDS:
//   A triple-buffered (sh[0..2]), B double-buffered (sh[3..4]).
// Counted-vmcnt 4-phase schedule per K-tile t (reads A from Ab[t%3],
// B from Bb[t%2]; bq register-held from ph1):
//   ph1: ds aq(q0)+bq(all); issue A(t+2).h0 -> Ab[(t+2)%3]  (freed at group
//        entry barrier: A(t-1) reads done)
//   ph2: ds aq(q1);         issue A(t+2).h1
//   ph3: ds aq(q2);         issue B(t+2).h0 -> Bb[t%2]      (freed after ph1)
//   ph4: ds aq(q3);         issue B(t+2).h1; vmcnt(8)+bar   (drains A(t+1),
//        B(t+1), both issued 4-7 phases earlier -> near-free; 8 loads stay
//        in flight across the barrier)
// Tail: vmcnt(0) once prefetch stops (t+2 >= NT).  Race-traced: every LDS
// write-target freed by a barrier preceding the issuing phase.
// MODE 1: epilogue exp(acc/8) -> bf16 store + per-row sums -> lsum[bx][16384]
// MODE 2: epilogue scale by 1/rowsum (sums 8 partials), fp32 out
// MODE 3: fused QKV: n-split by 768; Q|K plain stores; V stored TRANSPOSED
template <int MODE, typename CT>
__global__ __launch_bounds__(512, 2)
void gemm_bt(const u16* __restrict__ A, const u16* __restrict__ B,
             CT* __restrict__ C, int Kd, int lda, int ldb, int ldc,
             size_t strideA, size_t strideB, size_t strideC,
             float* __restrict__ lsum, u16* __restrict__ vtp) {
  __shared__ __align__(16) u16 sh[5][256 * 64];   // 160 KiB: A x3, B x2

  // ---- XCD swizzle ----
  const u32 gx = gridDim.x, gy = gridDim.y;
  const u32 lin = blockIdx.x + gx * (blockIdx.y + gy * blockIdx.z);
  const u32 nblk = gx * gy * gridDim.z;
  const u32 newlin = (lin & 7u) * (nblk >> 3) + (lin >> 3);
  const u32 bx = newlin % gx;
  const u32 tmp = newlin / gx;
  const u32 by = tmp % gy;
  const u32 bz = tmp / gy;

  const u16* Az = A + (size_t)bz * strideA;
  const u16* Bz = B + (size_t)bz * strideB;
  const int m0 = by * 256;
  const int n0g = bx * 256;
  int n0 = n0g;
  int matrix = 0;
  CT* Cz;
  if (MODE == 3) {             // n-split store: matrix = n0/768 (768 = 3*256)
    matrix = n0g / 768;
    Cz = C + (size_t)matrix * strideC;
    n0 = n0g % 768;
  } else {
    Cz = C + (size_t)bz * strideC;
  }

  const int tid = threadIdx.x;
  const int lane = tid & 63, wave = tid >> 6;
  const int wr = wave >> 2, wc = wave & 3;          // 2 x 4 wave grid
  const int wm = wr * 128, wn = wc * 64;            // per-wave 128x64 output
  const int lr = lane & 15, quad = lane >> 4;
  const int sr = lane >> 3;                         // staging sub-row 0..7
  const int sc = ((lane & 7) ^ sr) << 3;            // pre-swizzled src element

  const u16* gA = Az + (size_t)m0 * lda;
  const u16* gB = Bz + (size_t)n0g * ldb;

  f32x4 acc[8][4] = {};
  const int NT = Kd >> 6;

  auto stageA = [&](int buf, int half, int k0) {    // one half-tile: 128 rows
#pragma unroll
    for (int r = 0; r < 2; ++r) {
      const int rows = half * 128 + r * 64 + wave * 8;
      gload_lds16(gA + (size_t)(rows + sr) * lda + (k0 + sc), &sh[buf][rows * 64]);
    }
  };
  auto stageB = [&](int buf, int half, int k0) {
#pragma unroll
    for (int r = 0; r < 2; ++r) {
      const int rows = half * 128 + r * 64 + wave * 8;
      gload_lds16(gB + (size_t)(rows + sr) * ldb + (k0 + sc), &sh[3 + buf][rows * 64]);
    }
  };

  // ---- prologue: tiles 0,1 staged; wait tile 0 (8 loads stay in flight)
  stageA(0, 0, 0);  stageA(0, 1, 0);
  stageB(0, 0, 0);  stageB(0, 1, 0);
  stageA(1, 0, 64); stageA(1, 1, 64);
  stageB(1, 0, 64); stageB(1, 1, 64);
  asm volatile("s_waitcnt vmcnt(8)" ::: "memory");
  __builtin_amdgcn_s_barrier();

  int ab = 0, ab2 = 2;                    // A buf of tile t, tile t+2
  for (int t = 0; t < NT; ++t) {
    const char* sAc = (const char*)sh[ab];
    const char* sBc = (const char*)sh[3 + (t & 1)];
    const bool pf = (t + 2 < NT);
    const int kP = (t + 2) << 6;
    bf16x8 bq[4][2];
#pragma unroll
    for (int p = 0; p < 4; ++p) {
      bf16x8 aq[2][2];
#pragma unroll
      for (int mi = 0; mi < 2; ++mi)
#pragma unroll
        for (int kc = 0; kc < 2; ++kc)
          aq[mi][kc] = *(const bf16x8*)(sAc + (wm + (2 * p + mi) * 16 + lr) * 128 +
                                        ((((kc << 2) + quad) ^ (lr & 7)) << 4));
      if (p == 0) {
#pragma unroll
        for (int nt = 0; nt < 4; ++nt)
#pragma unroll
          for (int kc = 0; kc < 2; ++kc)
            bq[nt][kc] = *(const bf16x8*)(sBc + (wn + nt * 16 + lr) * 128 +
                                          ((((kc << 2) + quad) ^ (lr & 7)) << 4));
        if (pf) stageA(ab2, 0, kP);
      } else if (p == 1) {
        if (pf) stageA(ab2, 1, kP);
      } else if (p == 2) {
        if (pf) stageB(t & 1, 0, kP);
      } else {
        if (pf) stageB(t & 1, 1, kP);
      }
      __builtin_amdgcn_s_barrier();
      asm volatile("s_waitcnt lgkmcnt(0)" ::: "memory");
      __builtin_amdgcn_sched_barrier(0);
      __builtin_amdgcn_s_setprio(1);
#pragma unroll
      for (int mi = 0; mi < 2; ++mi)
#pragma unroll
        for (int nt = 0; nt < 4; ++nt)
#pragma unroll
          for (int kc = 0; kc < 2; ++kc)
            acc[2 * p + mi][nt] = __builtin_amdgcn_mfma_f32_16x16x32_bf16(
                aq[mi][kc], bq[nt][kc], acc[2 * p + mi][nt], 0, 0, 0);
      __builtin_amdgcn_s_setprio(0);
      if (p < 3) __builtin_amdgcn_s_barrier();
    }
    if (pf) asm volatile("s_waitcnt vmcnt(8)" ::: "memory");
    else    asm volatile("s_waitcnt vmcnt(0)" ::: "memory");
    __builtin_amdgcn_s_barrier();
    ab  = (ab  + 1 == 3) ? 0 : ab  + 1;
    ab2 = (ab2 + 1 == 3) ? 0 : ab2 + 1;
  }

  // ---- epilogues ----  C/D layout: col = lane&15, row = quad*4 + reg
  if (MODE == 1) {
    float* rowsum = (float*)sh;            // LDS reuse (post-barrier, drained)
    if (tid < 256) rowsum[tid] = 0.f;
    __syncthreads();
#pragma unroll
    for (int mt = 0; mt < 8; ++mt) {
#pragma unroll
      for (int i = 0; i < 4; ++i) {
        const int row_l = wm + mt * 16 + quad * 4 + i;
        CT* cp = Cz + (size_t)(m0 + row_l) * ldc + (n0 + wn + lr);
        float e[4], s = 0.f;
#pragma unroll
        for (int nt = 0; nt < 4; ++nt) {
          e[nt] = __expf(acc[mt][nt][i] * 0.125f);
          s += e[nt];
          cp[nt * 16] = f2bf(e[nt]);
        }
        s += __shfl_xor(s, 1);  s += __shfl_xor(s, 2);
        s += __shfl_xor(s, 4);  s += __shfl_xor(s, 8);   // 16-lane quad sum
        if (lr == 0) atomicAdd(&rowsum[row_l], s);
      }
    }
    __syncthreads();
    if (tid < 256)
      lsum[(size_t)bx * 16384 + (size_t)bz * 2048 + m0 + tid] = rowsum[tid];
  } else if (MODE == 2) {
    float* rinv = (float*)sh;              // LDS reuse (post-barrier, drained)
    if (tid < 256) {
      float s = 0.f;
      const size_t base = (size_t)bz * 2048 + m0 + tid;
#pragma unroll
      for (int xt = 0; xt < 8; ++xt) s += lsum[(size_t)xt * 16384 + base];
      rinv[tid] = 1.0f / s;
    }
    __syncthreads();
#pragma unroll
    for (int mt = 0; mt < 8; ++mt) {
#pragma unroll
      for (int i = 0; i < 4; ++i) {
        const int row_l = wm + mt * 16 + quad * 4 + i;
        const float iv = rinv[row_l];
        CT* cp = Cz + (size_t)(m0 + row_l) * ldc + (n0 + wn + lr);
#pragma unroll
        for (int nt = 0; nt < 4; ++nt) cp[nt * 16] = acc[mt][nt][i] * iv;
      }
    }
  } else if (MODE == 3 && matrix == 2) {
    // ---- V tile: store TRANSPOSED to vtp[b][o][t] via LDS ----
    u16* T = &sh[0][0];                    // first 128 KB = 256x256 u16 tile
#pragma unroll
    for (int mt = 0; mt < 8; ++mt) {
      const int rg = wr * 32 + mt * 4 + quad;          // row group (4 rows)
#pragma unroll
      for (int nt = 0; nt < 4; ++nt) {
        const int col = wn + nt * 16 + lr;
        u64 v = (u64)f2bf(acc[mt][nt][0])
              | ((u64)f2bf(acc[mt][nt][1]) << 16)
              | ((u64)f2bf(acc[mt][nt][2]) << 32)
              | ((u64)f2bf(acc[mt][nt][3]) << 48);
        *(u64*)((char*)T + col * 512 + ((rg ^ (col & 63)) << 3)) = v;
      }
    }
    __syncthreads();
    const int b = m0 >> 11;                // batch (256-row tile is within one)
#pragma unroll 4
    for (int it = 0; it < 32; ++it) {
      const int col = it * 8 + wave;
#pragma unroll
      for (int h = 0; h < 2; ++h) {
        const int rg = h * 32 + (lane >> 1);
        const u32 val = *(const u32*)((const char*)T + col * 512 +
                                      ((rg ^ (col & 63)) << 3) + ((lane & 1) << 2));
        *(u32*)(vtp + ((size_t)b * 768 + n0 + col) * 2048 +
                (m0 & 2047) + h * 128 + (lane << 1)) = val;
      }
    }
  } else {   // MODE 3 (Q/K) plain bf16 store
#pragma unroll
    for (int mt = 0; mt < 8; ++mt) {
#pragma unroll
      for (int i = 0; i < 4; ++i) {
        const int row_l = wm + mt * 16 + quad * 4 + i;
        CT* cp = Cz + (size_t)(m0 + row_l) * ldc + (n0 + wn + lr);
#pragma unroll
        for (int nt = 0; nt < 4; ++nt) cp[nt * 16] = f2bf(acc[mt][nt][i]);
      }
    }
  }
}

// ---------- launch ----------
extern "C" void kernel_launch(void* const* d_in, const int* in_sizes, int n_in,
                              void* d_out, int out_size, void* d_ws, size_t ws_size,
                              hipStream_t stream) {
  const float* x = (const float*)d_in[0];   // [8][2048][768]
  const float* w = (const float*)d_in[1];   // [3][768][768]
  float* out = (float*)d_out;               // [8][2048][768] fp32
  char* ws = (char*)d_ws;

  const size_t NS = (size_t)16384 * 768;
  u16* Sc = (u16*)ws;
  u16* Xb = (u16*)ws;
  u16* Wt = (u16*)(ws + NS * 2);
  u16* Qm = (u16*)(ws + 67108864);
  float* Lpart = (float*)(ws + 117440512);
  u16* Vt = (u16*)(ws + 142606336);

  // 1) prep: x -> bf16; W -> bf16 transposed Wt[(i*768+o)][d]
  prep<<<dim3(16, 16, 27), 256, 0, stream>>>(x, w, Xb, Wt);
  // 2) fused QKV projection: grid 9x64 = 576 blocks (%8==0)
  gemm_bt<3, u16><<<dim3(9, 64, 1), 512, 0, stream>>>(
      Xb, Wt, Qm, 768, 768, 768, 768, (size_t)0, (size_t)0, NS, Lpart, Vt);
  // 3) P = exp(Q K^T / 8) + row partial sums: grid 8x8x8 = 512 blocks
  gemm_bt<1, u16><<<dim3(8, 8, 8), 512, 0, stream>>>(
      Qm, Qm + NS, Sc, 768, 768, 768, 2048, (size_t)2048 * 768, (size_t)2048 * 768,
      (size_t)2048 * 2048, Lpart, nullptr);
  // 4) out = (P x V) / rowsum: grid 3x8x8 = 192 blocks
  gemm_bt<2, float><<<dim3(3, 8, 8), 512, 0, stream>>>(
      Sc, Vt, out, 2048, 2048, 2048, 768, (size_t)2048 * 2048,
      (size_t)768 * 2048, (size_t)2048 * 768, Lpart, nullptr);
}

// Round 4
// 279.826 us; speedup vs baseline: 1.0585x; 1.0585x over previous
//
#include <hip/hip_runtime.h>

typedef unsigned short u16;
typedef unsigned int   u32;
typedef unsigned long long u64;
typedef __bf16  bf16x8 __attribute__((ext_vector_type(8)));
typedef float   f32x4  __attribute__((ext_vector_type(4)));

// ---------- helpers ----------
__device__ __forceinline__ u16 f2bf(float f) {   // round-to-nearest-even
  u32 u = __builtin_bit_cast(u32, f);
  u += 0x7FFFu + ((u >> 16) & 1u);
  return (u16)(u >> 16);
}
__device__ __forceinline__ u32 pack2(float lo, float hi) {
  return (u32)f2bf(lo) | ((u32)f2bf(hi) << 16);
}

// async global->LDS, 16B per lane; LDS dest = wave-uniform base + lane*16
__device__ __forceinline__ void gload_lds16(const u16* g, u16* l) {
  __builtin_amdgcn_global_load_lds((const __attribute__((address_space(1))) void*)g,
                                   (__attribute__((address_space(3))) void*)l,
                                   16, 0, 0);
}

// ---------- prep: x fp32->bf16  AND  W fp32 -> bf16 transposed ----------
// grid (16,16,27): z<3 -> W-transpose (12x12 tiles of 64x64), z>=3 -> x cvt.
__global__ __launch_bounds__(256) void prep(const float* __restrict__ x,
                                            const float* __restrict__ w,
                                            u16* __restrict__ Xb,
                                            u16* __restrict__ Wt) {
  if (blockIdx.z < 3) {
    if (blockIdx.x >= 12 || blockIdx.y >= 12) return;
    __shared__ u16 t[64][65];
    const float* iz = w + (size_t)blockIdx.z * 768 * 768;
    u16* oz = Wt + (size_t)blockIdx.z * 768 * 768;
    const int tx = threadIdx.x & 63, ty = threadIdx.x >> 6;
    const int r0 = blockIdx.y * 64, c0 = blockIdx.x * 64;
#pragma unroll
    for (int rr = ty; rr < 64; rr += 4)
      t[rr][tx] = f2bf(iz[(size_t)(r0 + rr) * 768 + c0 + tx]);
    __syncthreads();
#pragma unroll
    for (int rr = ty; rr < 64; rr += 4)
      oz[(size_t)(c0 + rr) * 768 + r0 + tx] = t[tx][rr];
  } else {
    const size_t lin = (size_t)(blockIdx.z - 3) * 256 + blockIdx.y * 16 + blockIdx.x;
    const size_t i = lin * 256 + threadIdx.x;       // 8 elems per thread
    const float4* in4 = (const float4*)x;
    float4 a = in4[2 * i], b = in4[2 * i + 1];
    uint4 o;
    o.x = pack2(a.x, a.y); o.y = pack2(a.z, a.w);
    o.z = pack2(b.x, b.y); o.w = pack2(b.z, b.w);
    ((uint4*)Xb)[i] = o;
  }
}

// ---------- batched GEMM: C[m][n] = sum_k A[m][k] * Bt[n][k] ----------
// 128x128 tile, BK=64, 256 thr, XOR-swizzled LDS, XCD-aware block swizzle
// (each XCD owns a contiguous logical range; requires nblk % 8 == 0).
// MODE 1: epilogue exp(acc/8) -> bf16 store + per-row partial sums ->
//         lsum[bx][16384]  (softmax numerator; logits/8 max ~6.3, exp fits
//         fp32/bf16 comfortably -> no max-subtraction needed)
// MODE 2: epilogue scale by 1/rowsum (sums 16 partials from lsum), fp32 out
// MODE 3: fused QKV projection: n-split by 768 -> Q|K plain bf16 stores at
//         strideC apart; V (matrix 2) stored TRANSPOSED via LDS into
//         vtp[b][768][2048]  (deletes the separate V-transpose kernel)
template <int MODE, typename CT>
__global__ __launch_bounds__(256, 2)
void gemm_bt(const u16* __restrict__ A, const u16* __restrict__ B,
             CT* __restrict__ C, int Kd, int lda, int ldb, int ldc,
             size_t strideA, size_t strideB, size_t strideC,
             float* __restrict__ lsum, u16* __restrict__ vtp) {
  __shared__ __align__(16) u16 sh[2][128 * 64];   // sA = sh[0], sB = sh[1]
  u16* sA = sh[0];
  u16* sB = sh[1];

  // ---- XCD swizzle ----
  const u32 gx = gridDim.x, gy = gridDim.y;
  const u32 lin = blockIdx.x + gx * (blockIdx.y + gy * blockIdx.z);
  const u32 nblk = gx * gy * gridDim.z;
  const u32 newlin = (lin & 7u) * (nblk >> 3) + (lin >> 3);
  const u32 bx = newlin % gx;
  const u32 tmp = newlin / gx;
  const u32 by = tmp % gy;
  const u32 bz = tmp / gy;

  const u16* Az = A + (size_t)bz * strideA;
  const u16* Bz = B + (size_t)bz * strideB;
  const int m0 = by * 128;
  int n0 = bx * 128;
  int matrix = 0;
  CT* Cz;
  if (MODE == 3) {             // n-split store: matrix = n0/768
    matrix = n0 / 768;
    Cz = C + (size_t)matrix * strideC;
    n0 = n0 % 768;
  } else {
    Cz = C + (size_t)bz * strideC;
  }

  const int tid = threadIdx.x;
  const int lane = tid & 63, wave = tid >> 6;
  const int wm = (wave >> 1) * 64, wn = (wave & 1) * 64;
  const int lr = lane & 15, quad = lane >> 4;

  const u16* gA = Az + (size_t)(by * 128) * lda;
  const u16* gB = Bz + (size_t)(bx * 128) * ldb;
  const int stRow = wave * 8 + (lane >> 3);
  const int stCol = ((lane & 7) ^ (lane >> 3)) << 3;   // element offset in 64

  f32x4 acc[4][4] = {};

  for (int k0 = 0; k0 < Kd; k0 += 64) {
#pragma unroll
    for (int r = 0; r < 4; ++r) {
      gload_lds16(gA + (size_t)(stRow + r * 32) * lda + (k0 + stCol),
                  (u16*)((char*)sA + r * 4096 + wave * 1024));
      gload_lds16(gB + (size_t)(stRow + r * 32) * ldb + (k0 + stCol),
                  (u16*)((char*)sB + r * 4096 + wave * 1024));
    }
    __syncthreads();
#pragma unroll
    for (int kc = 0; kc < 2; ++kc) {
      bf16x8 af[4], bfv[4];
      const int coff = (((kc << 2) + quad) ^ (lr & 7)) << 4;  // swizzled byte offset
#pragma unroll
      for (int t = 0; t < 4; ++t) {
        af[t]  = *(const bf16x8*)((const char*)sA + (wm + t * 16 + lr) * 128 + coff);
        bfv[t] = *(const bf16x8*)((const char*)sB + (wn + t * 16 + lr) * 128 + coff);
      }
#pragma unroll
      for (int mt = 0; mt < 4; ++mt)
#pragma unroll
        for (int nt = 0; nt < 4; ++nt)
          acc[mt][nt] = __builtin_amdgcn_mfma_f32_16x16x32_bf16(
              af[mt], bfv[nt], acc[mt][nt], 0, 0, 0);
    }
    __syncthreads();
  }

  // ---- epilogues ----  C/D layout: col = lane&15, row = quad*4 + reg
  if (MODE == 1) {
    float* rowsum = (float*)sA;            // LDS reuse (post-barrier)
    if (tid < 128) rowsum[tid] = 0.f;
    __syncthreads();
#pragma unroll
    for (int mt = 0; mt < 4; ++mt) {
#pragma unroll
      for (int i = 0; i < 4; ++i) {
        const int row_l = wm + mt * 16 + quad * 4 + i;
        CT* cp = Cz + (size_t)(m0 + row_l) * ldc + (n0 + wn + lr);
        float e[4], s = 0.f;
#pragma unroll
        for (int nt = 0; nt < 4; ++nt) {
          e[nt] = __expf(acc[mt][nt][i] * 0.125f);
          s += e[nt];
          cp[nt * 16] = f2bf(e[nt]);
        }
        s += __shfl_xor(s, 1);  s += __shfl_xor(s, 2);
        s += __shfl_xor(s, 4);  s += __shfl_xor(s, 8);   // 16-lane quad sum
        if (lr == 0) atomicAdd(&rowsum[row_l], s);
      }
    }
    __syncthreads();
    if (tid < 128)
      lsum[(size_t)bx * 16384 + (size_t)bz * 2048 + m0 + tid] = rowsum[tid];
  } else if (MODE == 2) {
    float* rinv = (float*)sA;              // LDS reuse (post-barrier)
    if (tid < 128) {
      float s = 0.f;
      const size_t base = (size_t)bz * 2048 + m0 + tid;
#pragma unroll
      for (int xt = 0; xt < 16; ++xt) s += lsum[(size_t)xt * 16384 + base];
      rinv[tid] = 1.0f / s;
    }
    __syncthreads();
#pragma unroll
    for (int mt = 0; mt < 4; ++mt) {
#pragma unroll
      for (int i = 0; i < 4; ++i) {
        const int row_l = wm + mt * 16 + quad * 4 + i;
        const float iv = rinv[row_l];
        CT* cp = Cz + (size_t)(m0 + row_l) * ldc + (n0 + wn + lr);
#pragma unroll
        for (int nt = 0; nt < 4; ++nt) cp[nt * 16] = acc[mt][nt][i] * iv;
      }
    }
  } else if (MODE == 3 && matrix == 2) {
    // ---- V tile: store TRANSPOSED to vtp[b][o][t] via LDS ----
    // LDS phys: [col 0..127][row-group rg 0..31 XOR (col&31)][4 rows u16]
    u16* T = sh[0];                        // 32 KB = full 128x128 u16 tile
#pragma unroll
    for (int mt = 0; mt < 4; ++mt) {
      const int rg = (wave >> 1) * 16 + mt * 4 + quad;   // row group (4 rows)
#pragma unroll
      for (int nt = 0; nt < 4; ++nt) {
        const int col = wn + nt * 16 + lr;
        u64 v = (u64)f2bf(acc[mt][nt][0])
              | ((u64)f2bf(acc[mt][nt][1]) << 16)
              | ((u64)f2bf(acc[mt][nt][2]) << 32)
              | ((u64)f2bf(acc[mt][nt][3]) << 48);
        *(u64*)((char*)T + col * 256 + ((rg ^ (col & 31)) << 3)) = v;
      }
    }
    __syncthreads();
    const int b = m0 >> 11;                // batch (128-row tile is within one)
    const int t0 = (m0 & 2047) + (lane << 1);
    const int n0v = n0;                    // 0..640 within V's 768 cols
#pragma unroll
    for (int it = 0; it < 32; ++it) {
      const int col = it * 4 + wave;
      const u32 val = *(const u32*)((char*)T + col * 256 +
                                    (((lane >> 1) ^ (col & 31)) << 3) +
                                    ((lane & 1) << 2));
      *(u32*)(vtp + ((size_t)b * 768 + n0v + col) * 2048 + t0) = val;
    }
  } else {   // MODE 3 (Q/K) plain bf16 store
#pragma unroll
    for (int mt = 0; mt < 4; ++mt) {
#pragma unroll
      for (int i = 0; i < 4; ++i) {
        const int row_l = wm + mt * 16 + quad * 4 + i;
        CT* cp = Cz + (size_t)(m0 + row_l) * ldc + (n0 + wn + lr);
#pragma unroll
        for (int nt = 0; nt < 4; ++nt) cp[nt * 16] = f2bf(acc[mt][nt][i]);
      }
    }
  }
}

// ---------- launch ----------
extern "C" void kernel_launch(void* const* d_in, const int* in_sizes, int n_in,
                              void* d_out, int out_size, void* d_ws, size_t ws_size,
                              hipStream_t stream) {
  const float* x = (const float*)d_in[0];   // [8][2048][768]
  const float* w = (const float*)d_in[1];   // [3][768][768]
  float* out = (float*)d_out;               // [8][2048][768] fp32
  char* ws = (char*)d_ws;

  const size_t NS = (size_t)16384 * 768;
  // ws layout (bytes):
  //  [0, 67108864)              : Sc / P  bf16 [8][2048][2048]
  //    overlapped (dead before Sc is written):
  //    [0, 25165824)            : Xb bf16 [16384][768]
  //    [25165824, 28704768)     : Wt bf16 [2304][768]
  //  [67108864, 92274688)       : Q bf16 [16384][768]
  //  [92274688, 117440512)      : K bf16 [16384][768]
  //  [117440512, 118488832)     : Lpart fp32 [16][16384] (1 MB)
  //  [142606336, 167772160)     : Vt bf16 [8][768][2048]
  u16* Sc = (u16*)ws;
  u16* Xb = (u16*)ws;
  u16* Wt = (u16*)(ws + NS * 2);
  u16* Qm = (u16*)(ws + 67108864);
  u16* Km = Qm + NS;
  float* Lpart = (float*)(ws + 117440512);
  u16* Vt = (u16*)(ws + 142606336);

  // 1) prep: x -> bf16; W -> bf16 transposed Wt[(i*768+o)][d]
  prep<<<dim3(16, 16, 27), 256, 0, stream>>>(x, w, Xb, Wt);
  // 2) fused QKV projection (single pass over Xb): Q,K plain; V -> Vt fused
  gemm_bt<3, u16><<<dim3(18, 128, 1), 256, 0, stream>>>(
      Xb, Wt, Qm, 768, 768, 768, 768, (size_t)0, (size_t)0, NS, Lpart, Vt);
  // 3) P = exp(Q K^T / 8) (bf16, unnormalized) + row partial sums -> Lpart
  gemm_bt<1, u16><<<dim3(16, 16, 8), 256, 0, stream>>>(
      Qm, Km, Sc, 768, 768, 768, 2048, (size_t)2048 * 768, (size_t)2048 * 768,
      (size_t)2048 * 2048, Lpart, nullptr);
  // 4) out = (P x V) / rowsum  (A=P [2048][2048], Bt=Vt [768][2048]) -> fp32
  gemm_bt<2, float><<<dim3(6, 16, 8), 256, 0, stream>>>(
      Sc, Vt, out, 2048, 2048, 2048, 768, (size_t)2048 * 2048,
      (size_t)768 * 2048, (size_t)2048 * 768, Lpart, nullptr);
}